// Round 4
// baseline (132.214 us; speedup 1.0000x reference)
//
#include <hip/hip_runtime.h>
#include <math.h>

#define B_ 8
#define N_ 2048
#define NT_ (B_*N_)          // 16384 rows
#define OUTSZ (NT_*64)       // 1048576 elements per output tensor

// ---- workspace layout (float offsets); total ~9.1 MB, ws is 512 MiB ----
#define WS_XH    0                       // x_hidden f32 [NT_][64]
#define WS_ASRC  (WS_XH + NT_*64)
#define WS_ADST  (WS_ASRC + NT_)
#define WS_EJ    (WS_ADST + NT_)         // exp(adst_j)  [b*N_ + j]
#define WS_C1    (WS_EJ + NT_)           // exp(asrc_i - M_i)
#define WS_C2    (WS_C1 + NT_)           // exp(2*asrc_i - M_i)
#define WS_THR   (WS_C2 + NT_)           // exp(-asrc_i)
#define WS_GMAX  (WS_THR + NT_)
#define WS_WT    (WS_GMAX + 32)          // [128][256] fused gate weights (transposed)
#define WS_BB    (WS_WT + 128*256)       // [256] combined gate bias
#define WS_WOT   (WS_BB + 256)           // [128][64] Wout transposed
#define WS_C1D   (WS_WOT + 128*64)       // c1 / denom
#define WS_C2D   (WS_C1D + NT_)          // c2 / denom
#define WS_MASK  (WS_C2D + NT_)          // u32[NT_][64] adj bitmask (aliased)
// WhT bf16 [B][64][N] lives in d_out[0 .. 524288 floats) -- dead until k5 overwrites.

typedef float f32x4 __attribute__((ext_vector_type(4)));
typedef __bf16 bf16x8 __attribute__((ext_vector_type(8)));
typedef __bf16 bf16x4 __attribute__((ext_vector_type(4)));

__device__ __forceinline__ float lrelu2(float x) { return x > 0.f ? x : 2.f * x; }
__device__ __forceinline__ float f4get(const float4& v, int k) { return k==0?v.x:(k==1?v.y:(k==2?v.z:v.w)); }

// ---------------- K0: weight prep ----------------
__global__ void k0_prep(const float* Wf, const float* Wi, const float* Wo, const float* Wc,
                        const float* Uf, const float* Ui, const float* Uo, const float* Uc,
                        const float* bWf, const float* bWi, const float* bWo, const float* bWc,
                        const float* bUf, const float* bUi, const float* bUo, const float* bUc,
                        const float* Wout, float* ws)
{
    int idx = blockIdx.x * 256 + threadIdx.x;
    if (idx < 128 * 256) {
        int k = idx >> 8, o = idx & 255;
        int g = o >> 6, u = o & 63;
        const float* Wg = (g == 0) ? Wf : (g == 1) ? Wi : (g == 2) ? Wo : Wc;
        const float* Ug = (g == 0) ? Uf : (g == 1) ? Ui : (g == 2) ? Uo : Uc;
        ws[WS_WT + idx] = (k < 64) ? Wg[u * 64 + k] : Ug[u * 64 + (k - 64)];
    } else if (idx < 128 * 256 + 256) {
        int o = idx - 128 * 256;
        int g = o >> 6, u = o & 63;
        const float* bW = (g == 0) ? bWf : (g == 1) ? bWi : (g == 2) ? bWo : bWc;
        const float* bU = (g == 0) ? bUf : (g == 1) ? bUi : (g == 2) ? bUo : bUc;
        ws[WS_BB + o] = bW[u] + bU[u];
    } else if (idx < 128 * 256 + 256 + 128 * 64) {
        int j = idx - (128 * 256 + 256);
        int k = j >> 6, u = j & 63;
        ws[WS_WOT + j] = Wout[u * 128 + k];   // WoutT[k][u]
    }
}

// ---------------- K1: Wh = x@W -> WhT bf16 [b][h][j], a_src, a_dst ----------------
__global__ __launch_bounds__(256) void k1_wh(const float* __restrict__ x, const float* __restrict__ W,
                                             const float* __restrict__ a, float* __restrict__ ws,
                                             __bf16* __restrict__ whT)
{
    __shared__ float xl[64 * 68];
    __shared__ float Wl[64 * 68];
    int t = threadIdx.x;
    int i0 = blockIdx.x * 64;
    #pragma unroll
    for (int it = 0; it < 4; ++it) {
        int f = t + 256 * it;
        int r = f >> 4, q = f & 15;
        *(float4*)&xl[r * 68 + q * 4] = *(const float4*)&x[i0 * 64 + f * 4];
        *(float4*)&Wl[r * 68 + q * 4] = *(const float4*)&W[f * 4];
    }
    __syncthreads();
    int cg = t & 15, rg = t >> 4;
    int c0 = cg * 4, r0 = rg * 4;
    float acc[4][4] = {};
    #pragma unroll
    for (int d0 = 0; d0 < 64; d0 += 4) {
        float4 wv[4], xv[4];
        #pragma unroll
        for (int k = 0; k < 4; ++k) wv[k] = *(float4*)&Wl[(d0 + k) * 68 + c0];
        #pragma unroll
        for (int ri = 0; ri < 4; ++ri) xv[ri] = *(float4*)&xl[(r0 + ri) * 68 + d0];
        #pragma unroll
        for (int ri = 0; ri < 4; ++ri)
            #pragma unroll
            for (int k = 0; k < 4; ++k) {
                float xs = f4get(xv[ri], k);
                acc[ri][0] += xs * wv[k].x; acc[ri][1] += xs * wv[k].y;
                acc[ri][2] += xs * wv[k].z; acc[ri][3] += xs * wv[k].w;
            }
    }
    // transposed bf16 write: WhT[b][h=c0+cj][j=rowb0..+3]
    int b = i0 >> 11;
    int rowb0 = (i0 & 2047) + r0;
    #pragma unroll
    for (int cj = 0; cj < 4; ++cj) {
        bf16x4 v;
        v[0] = (__bf16)acc[0][cj]; v[1] = (__bf16)acc[1][cj];
        v[2] = (__bf16)acc[2][cj]; v[3] = (__bf16)acc[3][cj];
        *(bf16x4*)&whT[((size_t)(b * 64 + c0 + cj)) * N_ + rowb0] = v;
    }
    float4 a0 = *(const float4*)&a[c0];
    float4 a1 = *(const float4*)&a[64 + c0];
    #pragma unroll
    for (int ri = 0; ri < 4; ++ri) {
        int row = i0 + r0 + ri;
        float s0 = acc[ri][0]*a0.x + acc[ri][1]*a0.y + acc[ri][2]*a0.z + acc[ri][3]*a0.w;
        float s1 = acc[ri][0]*a1.x + acc[ri][1]*a1.y + acc[ri][2]*a1.z + acc[ri][3]*a1.w;
        #pragma unroll
        for (int m = 1; m < 16; m <<= 1) { s0 += __shfl_xor(s0, m, 64); s1 += __shfl_xor(s1, m, 64); }
        if (cg == 0) { ws[WS_ASRC + row] = s0; ws[WS_ADST + row] = s1; }
    }
}

// ---------------- K1b: per-batch gmax, Ej, per-row softmax constants ----------------
__global__ __launch_bounds__(256) void k1b_prep(float* ws)
{
    __shared__ float red[256];
    __shared__ float gsh;
    int b = blockIdx.x, t = threadIdx.x;
    float m = -3.0e38f;
    for (int j = t; j < N_; j += 256) {
        float v = ws[WS_ADST + b * N_ + j];
        ws[WS_EJ + b * N_ + j] = __expf(v);
        m = fmaxf(m, v);
    }
    red[t] = m; __syncthreads();
    for (int s = 128; s > 0; s >>= 1) { if (t < s) red[t] = fmaxf(red[t], red[t + s]); __syncthreads(); }
    if (t == 0) { gsh = red[0]; ws[WS_GMAX + b] = red[0]; }
    __syncthreads();
    float gmax = gsh;
    for (int i = t; i < N_; i += 256) {
        float as = ws[WS_ASRC + b * N_ + i];
        float M = lrelu2(as + gmax);
        ws[WS_C1 + b * N_ + i]  = __expf(as - M);
        ws[WS_C2 + b * N_ + i]  = __expf(2.f * as - M);
        ws[WS_THR + b * N_ + i] = __expf(-as);
    }
}

// ---------------- Kpack: adj -> bitmask + exact per-row denominator ----------------
// One wave per row. Lane l owns j in [l*32, l*32+32): builds one u32 mask word and
// accumulates s1 = sum(masked, s>0) Ej, s2 = sum(masked, s<=0) Ej^2.
// denom = c1*s1 + c2*s2 (algebraically == reference row sum). Stores c1/denom, c2/denom.
__global__ __launch_bounds__(256) void kpack(const float* __restrict__ adj, float* __restrict__ ws)
{
    int w = threadIdx.x >> 6, l = threadIdx.x & 63;
    int row = blockIdx.x * 4 + w;
    int b = row >> 11;
    const float* ar  = &adj[(size_t)row * N_];
    const float* ejp = &ws[WS_EJ + b * N_];
    float thr = ws[WS_THR + row];
    unsigned bits = 0u;
    float s1 = 0.f, s2 = 0.f;
    #pragma unroll
    for (int q = 0; q < 8; ++q) {
        int j = l * 32 + q * 4;
        float4 av = *(const float4*)&ar[j];
        float4 ej = *(const float4*)&ejp[j];
        #pragma unroll
        for (int e = 0; e < 4; ++e) {
            float a_ = f4get(av, e), E = f4get(ej, e);
            bool m_ = a_ > 0.f;
            bits |= m_ ? (1u << (q * 4 + e)) : 0u;
            bool t_ = E > thr;
            s1 += (m_ && t_) ? E : 0.f;
            s2 += (m_ && !t_) ? E * E : 0.f;
        }
    }
    #pragma unroll
    for (int m_ = 1; m_ < 64; m_ <<= 1) { s1 += __shfl_xor(s1, m_, 64); s2 += __shfl_xor(s2, m_, 64); }
    unsigned* mw = (unsigned*)&ws[WS_MASK];
    mw[(size_t)row * 64 + l] = bits;
    if (l == 0) {
        float c1 = ws[WS_C1 + row], c2 = ws[WS_C2 + row];
        float den = c1 * s1 + c2 * s2;
        float inv = den > 0.f ? 1.f / den : 0.f;
        ws[WS_C1D + row] = c1 * inv;
        ws[WS_C2D + row] = c2 * inv;
    }
}

// ---------------- K2m: softmax-weighted GEMM via MFMA, mask-driven, L2-only loads ----------------
// Block = one 16-row tile; 4 waves = 4 j-slices of 512. No adj reads (mask bits),
// p already normalized (c1d/c2d). LDS combine of the 4 slice-partials + ELU -> XH.
__global__ __launch_bounds__(256) void k2m(const __bf16* __restrict__ whT, float* __restrict__ ws)
{
    __shared__ float ls[4 * 16 * 64];
    int tid = threadIdx.x;
    int lane = tid & 63, w = tid >> 6;
    int r = lane & 15, g = lane >> 4;
    int row0 = blockIdx.x * 16;
    int b = row0 >> 11;
    int jbeg = w * (N_ / 4);

    float c1d = ws[WS_C1D + row0 + r];
    float c2d = ws[WS_C2D + row0 + r];
    float thr = ws[WS_THR + row0 + r];
    const unsigned* mrow = (const unsigned*)&ws[WS_MASK] + (size_t)(row0 + r) * 64 + (jbeg >> 5);
    const float* ejp = &ws[WS_EJ + b * N_ + jbeg];
    const __bf16* bb = &whT[((size_t)(b * 64 + r)) * N_ + jbeg];

    f32x4 acc0 = {0.f,0.f,0.f,0.f}, acc1 = {0.f,0.f,0.f,0.f};
    f32x4 acc2 = {0.f,0.f,0.f,0.f}, acc3 = {0.f,0.f,0.f,0.f};

    #pragma unroll 2
    for (int it = 0; it < 16; ++it) {
        int jk = it * 32 + g * 8;
        unsigned word = mrow[it];
        float4 e0 = *(const float4*)&ejp[jk];
        float4 e1 = *(const float4*)&ejp[jk + 4];
        bf16x8 b0 = *(const bf16x8*)&bb[jk];
        bf16x8 b1 = *(const bf16x8*)&bb[16 * N_ + jk];
        bf16x8 b2 = *(const bf16x8*)&bb[32 * N_ + jk];
        bf16x8 b3 = *(const bf16x8*)&bb[48 * N_ + jk];
        bf16x8 af;
        #pragma unroll
        for (int e = 0; e < 8; ++e) {
            float E = f4get(e < 4 ? e0 : e1, e & 3);
            float p = (E > thr) ? c1d * E : (c2d * E) * E;
            unsigned bit = (word >> (g * 8 + e)) & 1u;
            p = bit ? p : 0.f;
            af[e] = (__bf16)p;
        }
        acc0 = __builtin_amdgcn_mfma_f32_16x16x32_bf16(af, b0, acc0, 0, 0, 0);
        acc1 = __builtin_amdgcn_mfma_f32_16x16x32_bf16(af, b1, acc1, 0, 0, 0);
        acc2 = __builtin_amdgcn_mfma_f32_16x16x32_bf16(af, b2, acc2, 0, 0, 0);
        acc3 = __builtin_amdgcn_mfma_f32_16x16x32_bf16(af, b3, acc3, 0, 0, 0);
    }
    // partial -> LDS (C-layout: row=g*4+i, col=n*16+r)
    float* lw = &ls[w * 1024];
    #pragma unroll
    for (int i = 0; i < 4; ++i) {
        lw[(g * 4 + i) * 64 +  0 + r] = acc0[i];
        lw[(g * 4 + i) * 64 + 16 + r] = acc1[i];
        lw[(g * 4 + i) * 64 + 32 + r] = acc2[i];
        lw[(g * 4 + i) * 64 + 48 + r] = acc3[i];
    }
    __syncthreads();
    // combine 4 slices + ELU -> XH
    #pragma unroll
    for (int k = 0; k < 4; ++k) {
        int e = tid + k * 256;
        float v = ls[e] + ls[1024 + e] + ls[2048 + e] + ls[3072 + e];
        v = v > 0.f ? v : expm1f(v);
        ws[WS_XH + (size_t)row0 * 64 + e] = v;
    }
}

// ---------------- K3: LSTM gates + cell update. 16 rows/block ----------------
__global__ __launch_bounds__(256) void k3_lstm(const float* __restrict__ x, const float* __restrict__ c,
                                               const float* __restrict__ h, const float* __restrict__ ws,
                                               float* __restrict__ out)
{
    __shared__ float Al[16 * 132];   // [row][k]: k<64 = h, k>=64 = x
    __shared__ float gl[16 * 260];   // gate pre-activations [row][256]
    int t = threadIdx.x;
    int base = blockIdx.x * 16;
    {
        int r = t >> 4, k0 = (t & 15) * 8;
        const float* src = (k0 < 64) ? &h[(base + r) * 64 + k0] : &x[(base + r) * 64 + (k0 - 64)];
        *(float4*)&Al[r * 132 + k0]     = *(const float4*)&src[0];
        *(float4*)&Al[r * 132 + k0 + 4] = *(const float4*)&src[4];
    }
    __syncthreads();
    int og = t & 63, rg = t >> 6;
    int o0 = og * 4;
    const float* WT = &ws[WS_WT];
    float acc[4][4] = {};
    #pragma unroll
    for (int k0 = 0; k0 < 128; k0 += 4) {
        float4 wv[4], av[4];
        #pragma unroll
        for (int kk = 0; kk < 4; ++kk) wv[kk] = *(const float4*)&WT[(k0 + kk) * 256 + o0];
        #pragma unroll
        for (int rr = 0; rr < 4; ++rr) av[rr] = *(float4*)&Al[(rg + 4 * rr) * 132 + k0];
        #pragma unroll
        for (int rr = 0; rr < 4; ++rr)
            #pragma unroll
            for (int kk = 0; kk < 4; ++kk) {
                float as = f4get(av[rr], kk);
                acc[rr][0] += as * wv[kk].x; acc[rr][1] += as * wv[kk].y;
                acc[rr][2] += as * wv[kk].z; acc[rr][3] += as * wv[kk].w;
            }
    }
    float4 bbv = *(const float4*)&ws[WS_BB + o0];
    #pragma unroll
    for (int rr = 0; rr < 4; ++rr) {
        int r = rg + 4 * rr;
        *(float4*)&gl[r * 260 + o0] = make_float4(acc[rr][0] + bbv.x, acc[rr][1] + bbv.y,
                                                  acc[rr][2] + bbv.z, acc[rr][3] + bbv.w);
    }
    __syncthreads();
    int u = t & 63, rq = t >> 6;
    #pragma unroll
    for (int pp = 0; pp < 4; ++pp) {
        int r = rq + 4 * pp;
        float gf = gl[r * 260 + u];
        float gi = gl[r * 260 + 64 + u];
        float go = gl[r * 260 + 128 + u];
        float gc = gl[r * 260 + 192 + u];
        float fg = 1.f / (1.f + __expf(-gf));
        float ig = 1.f / (1.f + __expf(-gi));
        float oo = 1.f / (1.f + __expf(-go));
        float ch = tanhf(gc);
        float cv = c[(base + r) * 64 + u];
        float ct = fg * cv + ig * ch;
        float ht = oo * fmaxf(ct, 0.f);
        out[OUTSZ + (base + r) * 64 + u] = ht;
        out[2 * OUTSZ + (base + r) * 64 + u] = ct;
    }
}

// ---------------- K5: output = relu([x_hidden | h_t] @ WoutT + bout). 64 rows/block ----------------
__global__ __launch_bounds__(256) void k5_out(const float* __restrict__ ws, const float* __restrict__ bout,
                                              float* __restrict__ out)
{
    __shared__ float Al[64 * 132];
    int t = threadIdx.x;
    int base = blockIdx.x * 64;
    const float* xh = &ws[WS_XH];
    const float* ht = &out[OUTSZ];
    #pragma unroll
    for (int it = 0; it < 8; ++it) {
        int f = t + 256 * it;
        int r = f >> 5, q = f & 31;
        int k0 = q * 4;
        float4 v;
        if (k0 < 64) v = *(const float4*)&xh[(size_t)(base + r) * 64 + k0];
        else         v = *(const float4*)&ht[(size_t)(base + r) * 64 + (k0 - 64)];
        *(float4*)&Al[r * 132 + k0] = v;
    }
    __syncthreads();
    int cg = t & 15, rgG = t >> 4;
    int c0 = cg * 4, r0 = rgG * 4;
    const float* WT = &ws[WS_WOT];
    float acc[4][4] = {};
    #pragma unroll
    for (int k0 = 0; k0 < 128; k0 += 4) {
        float4 wv[4], av[4];
        #pragma unroll
        for (int kk = 0; kk < 4; ++kk) wv[kk] = *(const float4*)&WT[(k0 + kk) * 64 + c0];
        #pragma unroll
        for (int ri = 0; ri < 4; ++ri) av[ri] = *(float4*)&Al[(r0 + ri) * 132 + k0];
        #pragma unroll
        for (int ri = 0; ri < 4; ++ri)
            #pragma unroll
            for (int kk = 0; kk < 4; ++kk) {
                float as = f4get(av[ri], kk);
                acc[ri][0] += as * wv[kk].x; acc[ri][1] += as * wv[kk].y;
                acc[ri][2] += as * wv[kk].z; acc[ri][3] += as * wv[kk].w;
            }
    }
    float4 bo = *(const float4*)&bout[c0];
    #pragma unroll
    for (int ri = 0; ri < 4; ++ri) {
        int row = base + r0 + ri;
        float4 o;
        o.x = fmaxf(acc[ri][0] + bo.x, 0.f);
        o.y = fmaxf(acc[ri][1] + bo.y, 0.f);
        o.z = fmaxf(acc[ri][2] + bo.z, 0.f);
        o.w = fmaxf(acc[ri][3] + bo.w, 0.f);
        *(float4*)&out[row * 64 + c0] = o;
    }
}

extern "C" void kernel_launch(void* const* d_in, const int* in_sizes, int n_in,
                              void* d_out, int out_size, void* d_ws, size_t ws_size,
                              hipStream_t stream)
{
    const float* x    = (const float*)d_in[0];
    const float* adj  = (const float*)d_in[1];
    const float* c    = (const float*)d_in[2];
    const float* h    = (const float*)d_in[3];
    const float* W    = (const float*)d_in[4];
    const float* a    = (const float*)d_in[5];
    const float* Wf   = (const float*)d_in[6];
    const float* bWf  = (const float*)d_in[7];
    const float* Wi   = (const float*)d_in[8];
    const float* bWi  = (const float*)d_in[9];
    const float* Wo   = (const float*)d_in[10];
    const float* bWo  = (const float*)d_in[11];
    const float* Wc   = (const float*)d_in[12];
    const float* bWc  = (const float*)d_in[13];
    const float* Uf   = (const float*)d_in[14];
    const float* bUf  = (const float*)d_in[15];
    const float* Ui   = (const float*)d_in[16];
    const float* bUi  = (const float*)d_in[17];
    const float* Uo   = (const float*)d_in[18];
    const float* bUo  = (const float*)d_in[19];
    const float* Uc   = (const float*)d_in[20];
    const float* bUc  = (const float*)d_in[21];
    const float* Wout = (const float*)d_in[22];
    const float* bout = (const float*)d_in[23];
    float* out = (float*)d_out;
    float* ws  = (float*)d_ws;
    __bf16* whT = (__bf16*)out;   // WhT bf16 scratch in d_out segment 0; k5 overwrites last

    k0_prep<<<161, 256, 0, stream>>>(Wf, Wi, Wo, Wc, Uf, Ui, Uo, Uc,
                                     bWf, bWi, bWo, bWc, bUf, bUi, bUo, bUc, Wout, ws);
    k1_wh<<<NT_ / 64, 256, 0, stream>>>(x, W, a, ws, whT);
    k1b_prep<<<B_, 256, 0, stream>>>(ws);
    kpack<<<NT_ / 4, 256, 0, stream>>>(adj, ws);
    k3_lstm<<<NT_ / 16, 256, 0, stream>>>(x, c, h, ws, out);
    k2m<<<NT_ / 16, 256, 0, stream>>>(whT, ws);
    k5_out<<<NT_ / 64, 256, 0, stream>>>(ws, bout, out);
}

// Round 5
// 99.575 us; speedup vs baseline: 1.3278x; 1.3278x over previous
//
#include <hip/hip_runtime.h>
#include <math.h>

#define B_ 8
#define N_ 2048
#define NT_ (B_*N_)          // 16384 rows
#define OUTSZ (NT_*64)       // 1048576 elements per output tensor

// ---- workspace layout (float offsets) ----
#define WS_ASRC  0
#define WS_ADST  (WS_ASRC + NT_)
#define WS_EJ    (WS_ADST + NT_)         // exp(adst_j)  [b*N_ + j]
#define WS_C1    (WS_EJ + NT_)           // exp(asrc_i - M_i)
#define WS_C2    (WS_C1 + NT_)           // exp(2*asrc_i - M_i)
#define WS_THR   (WS_C2 + NT_)           // exp(-asrc_i)
#define WS_GMAX  (WS_THR + NT_)
#define WS_WT    (WS_GMAX + 32)          // [128][256] fused gate weights (transposed)
#define WS_BB    (WS_WT + 128*256)       // [256] combined gate bias
#define WS_WOT   (WS_BB + 256)           // [128][64] Wout transposed
#define WS_PD    (WS_WOT + 128*64)       // [8][NT_] partial denominators
#define WS_PN    (WS_PD + 8*NT_)         // [8][NT_][64] partial numerators (32 MB)
// WhT bf16 [B][64][N] lives in d_out[0 .. 524288 floats) -- dead until k5 overwrites.

typedef float f32x4 __attribute__((ext_vector_type(4)));
typedef __bf16 bf16x8 __attribute__((ext_vector_type(8)));
typedef __bf16 bf16x4 __attribute__((ext_vector_type(4)));

__device__ __forceinline__ float lrelu2(float x) { return x > 0.f ? x : 2.f * x; }
__device__ __forceinline__ float f4get(const float4& v, int k) { return k==0?v.x:(k==1?v.y:(k==2?v.z:v.w)); }

// ---------------- K0: weight prep ----------------
__global__ void k0_prep(const float* Wf, const float* Wi, const float* Wo, const float* Wc,
                        const float* Uf, const float* Ui, const float* Uo, const float* Uc,
                        const float* bWf, const float* bWi, const float* bWo, const float* bWc,
                        const float* bUf, const float* bUi, const float* bUo, const float* bUc,
                        const float* Wout, float* ws)
{
    int idx = blockIdx.x * 256 + threadIdx.x;
    if (idx < 128 * 256) {
        int k = idx >> 8, o = idx & 255;
        int g = o >> 6, u = o & 63;
        const float* Wg = (g == 0) ? Wf : (g == 1) ? Wi : (g == 2) ? Wo : Wc;
        const float* Ug = (g == 0) ? Uf : (g == 1) ? Ui : (g == 2) ? Uo : Uc;
        ws[WS_WT + idx] = (k < 64) ? Wg[u * 64 + k] : Ug[u * 64 + (k - 64)];
    } else if (idx < 128 * 256 + 256) {
        int o = idx - 128 * 256;
        int g = o >> 6, u = o & 63;
        const float* bW = (g == 0) ? bWf : (g == 1) ? bWi : (g == 2) ? bWo : bWc;
        const float* bU = (g == 0) ? bUf : (g == 1) ? bUi : (g == 2) ? bUo : bUc;
        ws[WS_BB + o] = bW[u] + bU[u];
    } else if (idx < 128 * 256 + 256 + 128 * 64) {
        int j = idx - (128 * 256 + 256);
        int k = j >> 6, u = j & 63;
        ws[WS_WOT + j] = Wout[u * 128 + k];   // WoutT[k][u]
    }
}

// ---------------- K1: Wh = x@W -> WhT bf16 [b][h][j], a_src, a_dst ----------------
__global__ __launch_bounds__(256) void k1_wh(const float* __restrict__ x, const float* __restrict__ W,
                                             const float* __restrict__ a, float* __restrict__ ws,
                                             __bf16* __restrict__ whT)
{
    __shared__ float xl[64 * 68];
    __shared__ float Wl[64 * 68];
    int t = threadIdx.x;
    int i0 = blockIdx.x * 64;
    #pragma unroll
    for (int it = 0; it < 4; ++it) {
        int f = t + 256 * it;
        int r = f >> 4, q = f & 15;
        *(float4*)&xl[r * 68 + q * 4] = *(const float4*)&x[i0 * 64 + f * 4];
        *(float4*)&Wl[r * 68 + q * 4] = *(const float4*)&W[f * 4];
    }
    __syncthreads();
    int cg = t & 15, rg = t >> 4;
    int c0 = cg * 4, r0 = rg * 4;
    float acc[4][4] = {};
    #pragma unroll
    for (int d0 = 0; d0 < 64; d0 += 4) {
        float4 wv[4], xv[4];
        #pragma unroll
        for (int k = 0; k < 4; ++k) wv[k] = *(float4*)&Wl[(d0 + k) * 68 + c0];
        #pragma unroll
        for (int ri = 0; ri < 4; ++ri) xv[ri] = *(float4*)&xl[(r0 + ri) * 68 + d0];
        #pragma unroll
        for (int ri = 0; ri < 4; ++ri)
            #pragma unroll
            for (int k = 0; k < 4; ++k) {
                float xs = f4get(xv[ri], k);
                acc[ri][0] += xs * wv[k].x; acc[ri][1] += xs * wv[k].y;
                acc[ri][2] += xs * wv[k].z; acc[ri][3] += xs * wv[k].w;
            }
    }
    // transposed bf16 write: WhT[b][h=c0+cj][j=rowb0..+3]
    int b = i0 >> 11;
    int rowb0 = (i0 & 2047) + r0;
    #pragma unroll
    for (int cj = 0; cj < 4; ++cj) {
        bf16x4 v;
        v[0] = (__bf16)acc[0][cj]; v[1] = (__bf16)acc[1][cj];
        v[2] = (__bf16)acc[2][cj]; v[3] = (__bf16)acc[3][cj];
        *(bf16x4*)&whT[((size_t)(b * 64 + c0 + cj)) * N_ + rowb0] = v;
    }
    float4 a0 = *(const float4*)&a[c0];
    float4 a1 = *(const float4*)&a[64 + c0];
    #pragma unroll
    for (int ri = 0; ri < 4; ++ri) {
        int row = i0 + r0 + ri;
        float s0 = acc[ri][0]*a0.x + acc[ri][1]*a0.y + acc[ri][2]*a0.z + acc[ri][3]*a0.w;
        float s1 = acc[ri][0]*a1.x + acc[ri][1]*a1.y + acc[ri][2]*a1.z + acc[ri][3]*a1.w;
        #pragma unroll
        for (int m = 1; m < 16; m <<= 1) { s0 += __shfl_xor(s0, m, 64); s1 += __shfl_xor(s1, m, 64); }
        if (cg == 0) { ws[WS_ASRC + row] = s0; ws[WS_ADST + row] = s1; }
    }
}

// ---------------- K1b: per-batch gmax, Ej, per-row softmax constants ----------------
__global__ __launch_bounds__(256) void k1b_prep(float* ws)
{
    __shared__ float red[256];
    __shared__ float gsh;
    int b = blockIdx.x, t = threadIdx.x;
    float m = -3.0e38f;
    for (int j = t; j < N_; j += 256) {
        float v = ws[WS_ADST + b * N_ + j];
        ws[WS_EJ + b * N_ + j] = __expf(v);
        m = fmaxf(m, v);
    }
    red[t] = m; __syncthreads();
    for (int s = 128; s > 0; s >>= 1) { if (t < s) red[t] = fmaxf(red[t], red[t + s]); __syncthreads(); }
    if (t == 0) { gsh = red[0]; ws[WS_GMAX + b] = red[0]; }
    __syncthreads();
    float gmax = gsh;
    for (int i = t; i < N_; i += 256) {
        float as = ws[WS_ASRC + b * N_ + i];
        float M = lrelu2(as + gmax);
        ws[WS_C1 + b * N_ + i]  = __expf(as - M);
        ws[WS_C2 + b * N_ + i]  = __expf(2.f * as - M);
        ws[WS_THR + b * N_ + i] = __expf(-as);
    }
}

// ---------------- K2v3: j-resident MFMA attention GEMM ----------------
// Block = (jr, b, 128-row slab). 4 waves each own a FIXED 64-j window (2 k-steps):
// B-frags (8x bf16x8) and Ej (16 f32) loaded ONCE; loop over 8 row-tiles reads only
// adj (4x float4, full-line-consumed) + 3 broadcast consts. Waves LDS-combine per
// tile -> one partial per jr. adj for tile t+1 issued before tile t's barriers.
__global__ __launch_bounds__(256) void k2v3(const float* __restrict__ adj,
                                            const __bf16* __restrict__ whT,
                                            float* __restrict__ ws)
{
    __shared__ float lsa[4][16][68];
    __shared__ float lsd[4][16];
    int tid = threadIdx.x;
    int lane = tid & 63, w = tid >> 6;
    int r = lane & 15, g = lane >> 4;
    int jr = blockIdx.x & 7;
    int rblk = blockIdx.x >> 3;           // 0..127
    int b = rblk >> 4;
    int row_base = b * N_ + (rblk & 15) * 128;
    int jbeg = jr * 256 + w * 64;

    // loop-invariant B-frags: lane -> col h = n*16 + r, k-window = ks*32 + g*8
    bf16x8 bfr[2][4];
    #pragma unroll
    for (int ks = 0; ks < 2; ++ks)
        #pragma unroll
        for (int n = 0; n < 4; ++n)
            bfr[ks][n] = *(const bf16x8*)&whT[(size_t)(b * 64 + n * 16 + r) * N_ + jbeg + ks * 32 + g * 8];
    // loop-invariant Ej registers
    float ejr[2][8];
    #pragma unroll
    for (int ks = 0; ks < 2; ++ks) {
        float4 e0 = *(const float4*)&ws[WS_EJ + b * N_ + jbeg + ks * 32 + g * 8];
        float4 e1 = *(const float4*)&ws[WS_EJ + b * N_ + jbeg + ks * 32 + g * 8 + 4];
        ejr[ks][0]=e0.x; ejr[ks][1]=e0.y; ejr[ks][2]=e0.z; ejr[ks][3]=e0.w;
        ejr[ks][4]=e1.x; ejr[ks][5]=e1.y; ejr[ks][6]=e1.z; ejr[ks][7]=e1.w;
    }

#define LDTILE(T, A0, A1, A2, A3, C1v, C2v, THv)                                   \
    {                                                                              \
        int row0_ = row_base + (T) * 16;                                           \
        const float* ap_ = &adj[(size_t)(row0_ + r) * N_ + jbeg];                  \
        A0 = *(const float4*)&ap_[g * 8];                                          \
        A1 = *(const float4*)&ap_[g * 8 + 4];                                      \
        A2 = *(const float4*)&ap_[32 + g * 8];                                     \
        A3 = *(const float4*)&ap_[32 + g * 8 + 4];                                 \
        C1v = ws[WS_C1 + row0_ + r];                                               \
        C2v = ws[WS_C2 + row0_ + r];                                               \
        THv = ws[WS_THR + row0_ + r];                                              \
    }

    float4 av0, av1, av2, av3; float c1, c2, thr;
    LDTILE(0, av0, av1, av2, av3, c1, c2, thr);

    for (int t = 0; t < 8; ++t) {
        int row0 = row_base + t * 16;
        f32x4 acc[4] = {{0.f,0.f,0.f,0.f},{0.f,0.f,0.f,0.f},{0.f,0.f,0.f,0.f},{0.f,0.f,0.f,0.f}};
        float dsum = 0.f;
        #pragma unroll
        for (int ks = 0; ks < 2; ++ks) {
            bf16x8 af;
            float ds_ = 0.f;
            #pragma unroll
            for (int e = 0; e < 8; ++e) {
                float avv = f4get(e < 4 ? (ks ? av2 : av0) : (ks ? av3 : av1), e & 3);
                float E = ejr[ks][e];
                float p = (E > thr) ? c1 * E : (c2 * E) * E;
                p = (avv > 0.f) ? p : 0.f;
                ds_ += p;
                af[e] = (__bf16)p;
            }
            dsum += ds_;
            #pragma unroll
            for (int n = 0; n < 4; ++n)
                acc[n] = __builtin_amdgcn_mfma_f32_16x16x32_bf16(af, bfr[ks][n], acc[n], 0, 0, 0);
        }
        // prefetch next tile's adj + consts (latency hidden under barriers/combine)
        float4 nv0, nv1, nv2, nv3; float n1, n2, n3;
        if (t < 7) { LDTILE(t + 1, nv0, nv1, nv2, nv3, n1, n2, n3); }
        // denominator: combine the 4 k-groups of this row
        dsum += __shfl_xor(dsum, 16, 64);
        dsum += __shfl_xor(dsum, 32, 64);
        // acc -> LDS  (C layout: out-row m = g*4+i, out-col h = n*16 + r)
        #pragma unroll
        for (int n = 0; n < 4; ++n)
            #pragma unroll
            for (int i = 0; i < 4; ++i)
                lsa[w][g * 4 + i][n * 16 + r] = acc[n][i];
        if (g == 0) lsd[w][r] = dsum;
        __syncthreads();
        {
            int rl = tid >> 4, h0 = (tid & 15) * 4;
            float4 s = make_float4(0.f, 0.f, 0.f, 0.f);
            #pragma unroll
            for (int w2 = 0; w2 < 4; ++w2) {
                float4 q = *(const float4*)&lsa[w2][rl][h0];
                s.x += q.x; s.y += q.y; s.z += q.z; s.w += q.w;
            }
            *(float4*)&ws[WS_PN + ((size_t)jr * NT_ + row0 + rl) * 64 + h0] = s;
            if (tid < 16)
                ws[WS_PD + jr * NT_ + row0 + tid] = lsd[0][tid] + lsd[1][tid] + lsd[2][tid] + lsd[3][tid];
        }
        __syncthreads();
        av0 = nv0; av1 = nv1; av2 = nv2; av3 = nv3; c1 = n1; c2 = n2; thr = n3;
    }
#undef LDTILE
}

// ---------------- K3: LSTM gates + cell update. 16 rows/block ----------------
__global__ __launch_bounds__(256) void k3_lstm(const float* __restrict__ x, const float* __restrict__ c,
                                               const float* __restrict__ h, const float* __restrict__ ws,
                                               float* __restrict__ out)
{
    __shared__ float Al[16 * 132];   // [row][k]: k<64 = h, k>=64 = x
    __shared__ float gl[16 * 260];   // gate pre-activations [row][256]
    int t = threadIdx.x;
    int base = blockIdx.x * 16;
    {
        int r = t >> 4, k0 = (t & 15) * 8;
        const float* src = (k0 < 64) ? &h[(base + r) * 64 + k0] : &x[(base + r) * 64 + (k0 - 64)];
        *(float4*)&Al[r * 132 + k0]     = *(const float4*)&src[0];
        *(float4*)&Al[r * 132 + k0 + 4] = *(const float4*)&src[4];
    }
    __syncthreads();
    int og = t & 63, rg = t >> 6;
    int o0 = og * 4;
    const float* WT = &ws[WS_WT];
    float acc[4][4] = {};
    #pragma unroll
    for (int k0 = 0; k0 < 128; k0 += 4) {
        float4 wv[4], av[4];
        #pragma unroll
        for (int kk = 0; kk < 4; ++kk) wv[kk] = *(const float4*)&WT[(k0 + kk) * 256 + o0];
        #pragma unroll
        for (int rr = 0; rr < 4; ++rr) av[rr] = *(float4*)&Al[(rg + 4 * rr) * 132 + k0];
        #pragma unroll
        for (int rr = 0; rr < 4; ++rr)
            #pragma unroll
            for (int kk = 0; kk < 4; ++kk) {
                float as = f4get(av[rr], kk);
                acc[rr][0] += as * wv[kk].x; acc[rr][1] += as * wv[kk].y;
                acc[rr][2] += as * wv[kk].z; acc[rr][3] += as * wv[kk].w;
            }
    }
    float4 bbv = *(const float4*)&ws[WS_BB + o0];
    #pragma unroll
    for (int rr = 0; rr < 4; ++rr) {
        int r = rg + 4 * rr;
        *(float4*)&gl[r * 260 + o0] = make_float4(acc[rr][0] + bbv.x, acc[rr][1] + bbv.y,
                                                  acc[rr][2] + bbv.z, acc[rr][3] + bbv.w);
    }
    __syncthreads();
    int u = t & 63, rq = t >> 6;
    #pragma unroll
    for (int pp = 0; pp < 4; ++pp) {
        int r = rq + 4 * pp;
        float gf = gl[r * 260 + u];
        float gi = gl[r * 260 + 64 + u];
        float go = gl[r * 260 + 128 + u];
        float gc = gl[r * 260 + 192 + u];
        float fg = 1.f / (1.f + __expf(-gf));
        float ig = 1.f / (1.f + __expf(-gi));
        float oo = 1.f / (1.f + __expf(-go));
        float ch = tanhf(gc);
        float cv = c[(base + r) * 64 + u];
        float ct = fg * cv + ig * ch;
        float ht = oo * fmaxf(ct, 0.f);
        out[OUTSZ + (base + r) * 64 + u] = ht;
        out[2 * OUTSZ + (base + r) * 64 + u] = ct;
    }
}

// ---------------- K5: combine 8 partials -> x_hidden, then relu([xh | h_t] @ WoutT + bout) ----------------
__global__ __launch_bounds__(256) void k5_out(const float* __restrict__ ws, const float* __restrict__ bout,
                                              float* __restrict__ out)
{
    __shared__ float Al[64 * 132];
    int t = threadIdx.x;
    int base = blockIdx.x * 64;
    const float* ht = &out[OUTSZ];
    #pragma unroll
    for (int it = 0; it < 8; ++it) {
        int f = t + 256 * it;
        int r = f >> 5, q = f & 31;
        int k0 = q * 4;
        int row = base + r;
        float4 v;
        if (k0 < 64) {
            float4 s = make_float4(0.f, 0.f, 0.f, 0.f);
            float d = 0.f;
            #pragma unroll
            for (int jr = 0; jr < 8; ++jr) {
                float4 p = *(const float4*)&ws[WS_PN + ((size_t)jr * NT_ + row) * 64 + k0];
                s.x += p.x; s.y += p.y; s.z += p.z; s.w += p.w;
                d += ws[WS_PD + jr * NT_ + row];
            }
            float inv = 1.f / d;
            v.x = s.x * inv; v.x = v.x > 0.f ? v.x : expm1f(v.x);
            v.y = s.y * inv; v.y = v.y > 0.f ? v.y : expm1f(v.y);
            v.z = s.z * inv; v.z = v.z > 0.f ? v.z : expm1f(v.z);
            v.w = s.w * inv; v.w = v.w > 0.f ? v.w : expm1f(v.w);
        } else {
            v = *(const float4*)&ht[(size_t)row * 64 + (k0 - 64)];
        }
        *(float4*)&Al[r * 132 + k0] = v;
    }
    __syncthreads();
    int cg = t & 15, rgG = t >> 4;
    int c0 = cg * 4, r0 = rgG * 4;
    const float* WT = &ws[WS_WOT];
    float acc[4][4] = {};
    #pragma unroll
    for (int k0 = 0; k0 < 128; k0 += 4) {
        float4 wv[4], av[4];
        #pragma unroll
        for (int kk = 0; kk < 4; ++kk) wv[kk] = *(const float4*)&WT[(k0 + kk) * 64 + c0];
        #pragma unroll
        for (int ri = 0; ri < 4; ++ri) av[ri] = *(float4*)&Al[(r0 + ri) * 132 + k0];
        #pragma unroll
        for (int ri = 0; ri < 4; ++ri)
            #pragma unroll
            for (int kk = 0; kk < 4; ++kk) {
                float as = f4get(av[ri], kk);
                acc[ri][0] += as * wv[kk].x; acc[ri][1] += as * wv[kk].y;
                acc[ri][2] += as * wv[kk].z; acc[ri][3] += as * wv[kk].w;
            }
    }
    float4 bo = *(const float4*)&bout[c0];
    #pragma unroll
    for (int ri = 0; ri < 4; ++ri) {
        int row = base + r0 + ri;
        float4 o;
        o.x = fmaxf(acc[ri][0] + bo.x, 0.f);
        o.y = fmaxf(acc[ri][1] + bo.y, 0.f);
        o.z = fmaxf(acc[ri][2] + bo.z, 0.f);
        o.w = fmaxf(acc[ri][3] + bo.w, 0.f);
        *(float4*)&out[row * 64 + c0] = o;
    }
}

extern "C" void kernel_launch(void* const* d_in, const int* in_sizes, int n_in,
                              void* d_out, int out_size, void* d_ws, size_t ws_size,
                              hipStream_t stream)
{
    const float* x    = (const float*)d_in[0];
    const float* adj  = (const float*)d_in[1];
    const float* c    = (const float*)d_in[2];
    const float* h    = (const float*)d_in[3];
    const float* W    = (const float*)d_in[4];
    const float* a    = (const float*)d_in[5];
    const float* Wf   = (const float*)d_in[6];
    const float* bWf  = (const float*)d_in[7];
    const float* Wi   = (const float*)d_in[8];
    const float* bWi  = (const float*)d_in[9];
    const float* Wo   = (const float*)d_in[10];
    const float* bWo  = (const float*)d_in[11];
    const float* Wc   = (const float*)d_in[12];
    const float* bWc  = (const float*)d_in[13];
    const float* Uf   = (const float*)d_in[14];
    const float* bUf  = (const float*)d_in[15];
    const float* Ui   = (const float*)d_in[16];
    const float* bUi  = (const float*)d_in[17];
    const float* Uo   = (const float*)d_in[18];
    const float* bUo  = (const float*)d_in[19];
    const float* Uc   = (const float*)d_in[20];
    const float* bUc  = (const float*)d_in[21];
    const float* Wout = (const float*)d_in[22];
    const float* bout = (const float*)d_in[23];
    float* out = (float*)d_out;
    float* ws  = (float*)d_ws;
    __bf16* whT = (__bf16*)out;   // WhT bf16 scratch in d_out segment 0; k5 overwrites last

    k0_prep<<<161, 256, 0, stream>>>(Wf, Wi, Wo, Wc, Uf, Ui, Uo, Uc,
                                     bWf, bWi, bWo, bWc, bUf, bUi, bUo, bUc, Wout, ws);
    k1_wh<<<NT_ / 64, 256, 0, stream>>>(x, W, a, ws, whT);
    k1b_prep<<<B_, 256, 0, stream>>>(ws);
    k3_lstm<<<NT_ / 16, 256, 0, stream>>>(x, c, h, ws, out);
    k2v3<<<1024, 256, 0, stream>>>(adj, whT, ws);
    k5_out<<<NT_ / 64, 256, 0, stream>>>(ws, bout, out);
}